// Round 17
// baseline (111.576 us; speedup 1.0000x reference)
//
#include <hip/hip_runtime.h>

// ---------------------------------------------------------------------------
// Attention_25254407701324: full MHA forward on MI355X (gfx950).
// B=2, N=2048, E=1024, H=16, D=64.  bf16 MFMA, fp32 accum.
// R17: dedicated gemm_o with 128x64 tiles -> 512 blocks = 2 blocks/CU
//      (was 1 block/CU = 2 waves/SIMD, lowest occupancy in the file).
//      N-split doubles only A-panel re-reads, which are L2-resident by
//      construction (R10's M-split doubled L3 weight traffic -> lost).
//      qkv (R16 transposed-grid 128^2 dbuf) + flash (R15 fixed-max) frozen.
// ---------------------------------------------------------------------------

typedef __bf16 bf16x8 __attribute__((ext_vector_type(8)));
typedef float  f32x4  __attribute__((ext_vector_type(4)));
typedef float  f32x16 __attribute__((ext_vector_type(16)));
using u16 = unsigned short;
using u32 = unsigned int;
typedef u16 u16x8 __attribute__((ext_vector_type(8)));
typedef u16 u16x4 __attribute__((ext_vector_type(4)));
typedef u32 u32x4 __attribute__((ext_vector_type(4)));

constexpr int BATCH = 2, SEQ = 2048, EMB = 1024, NH = 16, HD = 64;
constexpr int MTOT = BATCH * SEQ;      // 4096
constexpr int KTOT = EMB;              // 1024
constexpr int NTOT = EMB;              // 1024
constexpr float LOG2E = 1.44269504088896340736f;
constexpr float FMAX2 = 32.0f;         // fixed base-2 softmax shift

// ws layout (bytes)
constexpr size_t OFF_XBF = 0;                         // 8 MB (reused as O)
constexpr size_t OFF_WQ  = 8u * 1024 * 1024;
constexpr size_t OFF_WK  = OFF_WQ + 2u * 1024 * 1024;
constexpr size_t OFF_WV  = OFF_WK + 2u * 1024 * 1024;
constexpr size_t OFF_WO  = OFF_WV + 2u * 1024 * 1024;
constexpr size_t OFF_Q   = OFF_WO + 2u * 1024 * 1024; // 16 MB
constexpr size_t OFF_K   = OFF_Q  + 8u * 1024 * 1024;
constexpr size_t OFF_VT  = OFF_K  + 8u * 1024 * 1024; // ends at 40 MB

__device__ __forceinline__ u16 f2bf(float f) {
  u32 u = __builtin_bit_cast(u32, f);
  u = (u + 0x7fffu + ((u >> 16) & 1u)) >> 16;   // RNE
  return (u16)u;
}

__device__ __forceinline__ bf16x8 ld_bf16x8(const u16* p) {
  return __builtin_bit_cast(bf16x8, *(const u16x8*)p);
}

__device__ __forceinline__ float fexp2(float x) {
#if __has_builtin(__builtin_amdgcn_exp2f)
  return __builtin_amdgcn_exp2f(x);
#else
  return exp2f(x);
#endif
}

// packed f32x2 -> bf16x2 (RNE), low word = first arg
__device__ __forceinline__ u32 cvtpk(float lo, float hi_) {
  u32 r;
  asm("v_cvt_pk_bf16_f32 %0, %1, %2" : "=v"(r) : "v"(lo), "v"(hi_));
  return r;
}

// async global->LDS, 16B per lane. LDS dest = wave-uniform base + lane*16.
__device__ __forceinline__ void stage16(const void* g, void* l) {
#if __has_builtin(__builtin_amdgcn_global_load_lds)
  __builtin_amdgcn_global_load_lds(
      (__attribute__((address_space(1))) void*)const_cast<void*>(g),
      (__attribute__((address_space(3))) void*)l, 16, 0, 0);
#else
  int lane = threadIdx.x & 63;
  uint4 v = *(const uint4*)g;
  *(uint4*)((char*)l + lane * 16) = v;
#endif
}

// ---------------------------------------------------------------------------
// fp32 -> bf16 for x and the 4 weight matrices; exact flat grid (8192 blocks).
__global__ __launch_bounds__(256) void cvt_all(
    const float* __restrict__ x, const float* __restrict__ wq,
    const float* __restrict__ wk, const float* __restrict__ wv,
    const float* __restrict__ wo, u16* __restrict__ ox, u16* __restrict__ oq,
    u16* __restrict__ okk, u16* __restrict__ ov, u16* __restrict__ oo) {
  int id = blockIdx.x;
  const float* in;
  u16* out;
  int i;
  if (id < 4096) {                 // x: 4096 blocks
    in = x; out = ox; i = id * 256 + threadIdx.x;
  } else {                         // weights: 1024 blocks each
    int z = (id - 4096) >> 10, r = (id - 4096) & 1023;
    in = (z == 0) ? wq : (z == 1) ? wk : (z == 2) ? wv : wo;
    out = (z == 0) ? oq : (z == 1) ? okk : (z == 2) ? ov : oo;
    i = r * 256 + threadIdx.x;
  }
  float4 f = ((const float4*)in)[i];
  u32 lo = (u32)f2bf(f.x) | ((u32)f2bf(f.y) << 16);
  u32 hi = (u32)f2bf(f.z) | ((u32)f2bf(f.w) << 16);
  ((uint2*)out)[i] = make_uint2(lo, hi);
}

// ---------------------------------------------------------------------------
// C = A[M][K] * B^T + bias, Bm is [N][K].  128x128 tile, 8 waves (512 thr).
// Grid is (M/128, N/128): blockIdx.x = m-tile (XCD = m-tile % 8 -> panels
// L2-resident), blockIdx.y = n-tile.  Double-buffered LDS, 1 barrier/K-step.
// Runtime mode (branch ONLY in epilogue):
// 0: bf16 scatter -> [B][H][N][D] (Q,K; oscale applied before cvt)
// 1: bf16 -> [B][H][D][N] (V^T) via LDS-transpose epilogue, coalesced stores
__device__ __forceinline__ void gemm_bt_core(const u16* __restrict__ A,
                                             const u16* __restrict__ Bm,
                                             const float* __restrict__ bias,
                                             void* __restrict__ out, int mode,
                                             float oscale) {
  __shared__ __align__(16) u16 smem[2][2][128 * 32];   // [buf][A/B] 32 KB
  const int tid = threadIdx.x, w = tid >> 6, ln = tid & 63;
  const int wr = w >> 1, wc = w & 1, qq = ln >> 4, t = ln & 15;
  const int m0 = blockIdx.x * 128, n0 = blockIdx.y * 128;   // transposed grid

  f32x4 acc[2][4] = {};

#define GSTAGE(bi, kt)                                                         \
  {                                                                            \
    int ck = w * 64 + ln;                        /* 0..511 */                  \
    int r = ck >> 2, c2 = ck & 3;                                              \
    stage16(&A[(size_t)(m0 + r) * KTOT + (kt) + c2 * 8],                       \
            &smem[bi][0][(size_t)(w * 64) * 8]);                               \
    stage16(&Bm[(size_t)(n0 + r) * KTOT + (kt) + c2 * 8],                      \
            &smem[bi][1][(size_t)(w * 64) * 8]);                               \
  }

  GSTAGE(0, 0)
  __syncthreads();

  int bs = 0;
  for (int kt = 0; kt < KTOT; kt += 32, bs ^= 1) {
    if (kt + 32 < KTOT) GSTAGE(bs ^ 1, kt + 32)
    const u16* sA = smem[bs][0];
    const u16* sB = smem[bs][1];

    bf16x8 av[2], bv[4];
#pragma unroll
    for (int f = 0; f < 2; f++)
      av[f] = ld_bf16x8(&sA[(wr * 32 + f * 16 + t) * 32 + qq * 8]);
#pragma unroll
    for (int f = 0; f < 4; f++)
      bv[f] = ld_bf16x8(&sB[(wc * 64 + f * 16 + t) * 32 + qq * 8]);
#pragma unroll
    for (int i = 0; i < 2; i++)
#pragma unroll
      for (int j = 0; j < 4; j++)
        acc[i][j] = __builtin_amdgcn_mfma_f32_16x16x32_bf16(av[i], bv[j], acc[i][j], 0, 0, 0);
    __syncthreads();   // stage(bs^1) landed; all reads of smem[bs] done
  }
#undef GSTAGE

  if (mode == 1) {
    // V^T: transpose the 128x128 tile through LDS (two 64-n-row phases),
    // then store tok-contiguous 16B/lane (256B segments).
    u16* tb = (u16*)smem;                       // 16 KB: [64 n][128 m] bf16
    const int b = m0 >> 11;
    const int t16 = tid & 15;
    const int tokb = (m0 & 2047) + t16 * 8;
#pragma unroll
    for (int ph = 0; ph < 2; ph++) {
      if (ph == 1) __syncthreads();             // protect ph0 reads
      if (wc == ph) {
#pragma unroll
        for (int fc = 0; fc < 4; fc++) {
          int nl = fc * 16 + t;
          float bn = bias[n0 + ph * 64 + nl];
#pragma unroll
          for (int fr = 0; fr < 2; fr++)
#pragma unroll
            for (int i = 0; i < 4; i++) {
              int ml = wr * 32 + fr * 16 + qq * 4 + i;
              tb[nl * 128 + (ml ^ ((nl & 7) << 4))] = f2bf(acc[fr][fc][i] + bn);
            }
        }
      }
      __syncthreads();
      // 512 threads: 32 rows/pass x 16 lanes, 2 passes -> 64 rows
#pragma unroll
      for (int p = 0; p < 2; p++) {
        int row = p * 32 + (tid >> 4);          // 0..63
        int n = n0 + ph * 64 + row;
        int hh = n >> 6, d = n & 63;
        u16x8 vd = *(const u16x8*)&tb[row * 128 + ((t16 * 8) ^ ((row & 7) << 4))];
        *(u16x8*)&((u16*)out)[(((size_t)(b * NH + hh)) * HD + d) * SEQ + tokb] = vd;
      }
    }
    return;
  }

#pragma unroll
  for (int fc = 0; fc < 4; fc++) {
    int n = n0 + wc * 64 + fc * 16 + t;
    float bn = bias[n];
#pragma unroll
    for (int fr = 0; fr < 2; fr++) {
#pragma unroll
      for (int i = 0; i < 4; i++) {
        int m = m0 + wr * 32 + fr * 16 + qq * 4 + i;
        float v = (acc[fr][fc][i] + bn) * oscale;
        int b = m >> 11, tok = m & 2047, h = n >> 6, d = n & 63;
        ((u16*)out)[(((size_t)(b * NH + h)) * SEQ + tok) * HD + d] = f2bf(v);
      }
    }
  }
}

// One launch, 3 z-slices, ONE call site -> one shared body.
__global__ __launch_bounds__(512) void gemm_qkv(
    const u16* __restrict__ A, const u16* __restrict__ WQ, const u16* __restrict__ WK,
    const u16* __restrict__ WV, const float* __restrict__ bq, const float* __restrict__ bk,
    const float* __restrict__ bv, u16* Qo, u16* Ko, u16* Vo) {
  int z = blockIdx.z;
  const u16* Bm = (z == 0) ? WQ : ((z == 1) ? WK : WV);
  const float* bias = (z == 0) ? bq : ((z == 1) ? bk : bv);
  u16* out = (z == 0) ? Qo : ((z == 1) ? Ko : Vo);
  // Q pre-scaled by log2(e) so flash softmax runs in base-2.
  gemm_bt_core(A, Bm, bias, out, (z == 2) ? 1 : 0, (z == 0) ? LOG2E : 1.0f);
}

// ---------------------------------------------------------------------------
// Output projection: 128x64 tile -> grid (32, 16) = 512 blocks = 2 blocks/CU
// (4 waves/SIMD, double the 128x128 version).  N-split doubles only A-panel
// re-reads (L2-resident).  8 waves, wave w owns rows w*16..w*16+15.
// Double-buffered, 1 barrier/K-step.  fp32 output + bias.
__global__ __launch_bounds__(512) void gemm_o(const u16* __restrict__ A,
                                              const u16* __restrict__ WO,
                                              const float* __restrict__ bo,
                                              float* __restrict__ out) {
  __shared__ __align__(16) u16 sA[2][128 * 32];   // 8 KB per buf
  __shared__ __align__(16) u16 sB[2][64 * 32];    // 4 KB per buf
  const int tid = threadIdx.x, w = tid >> 6, ln = tid & 63;
  const int qq = ln >> 4, t = ln & 15;
  const int m0 = blockIdx.x * 128, n0 = blockIdx.y * 64;

  f32x4 acc[4] = {};

#define OSTAGE(bi, kt)                                                         \
  {                                                                            \
    int ck = w * 64 + ln;                        /* 0..511 */                  \
    int rA = ck >> 2, cA = ck & 3;                                             \
    stage16(&A[(size_t)(m0 + rA) * KTOT + (kt) + cA * 8],                      \
            &sA[bi][(size_t)(w * 64) * 8]);                                    \
    if (w < 4) {                                 /* B: 256 chunks */           \
      int rB = ck >> 2, cB = ck & 3;                                           \
      stage16(&WO[(size_t)(n0 + rB) * KTOT + (kt) + cB * 8],                   \
              &sB[bi][(size_t)(w * 64) * 8]);                                  \
    }                                                                          \
  }

  OSTAGE(0, 0)
  __syncthreads();

  int bs = 0;
  for (int kt = 0; kt < KTOT; kt += 32, bs ^= 1) {
    if (kt + 32 < KTOT) OSTAGE(bs ^ 1, kt + 32)

    bf16x8 av = ld_bf16x8(&sA[bs][(w * 16 + t) * 32 + qq * 8]);
    bf16x8 bv[4];
#pragma unroll
    for (int f = 0; f < 4; f++)
      bv[f] = ld_bf16x8(&sB[bs][(f * 16 + t) * 32 + qq * 8]);
#pragma unroll
    for (int j = 0; j < 4; j++)
      acc[j] = __builtin_amdgcn_mfma_f32_16x16x32_bf16(av, bv[j], acc[j], 0, 0, 0);
    __syncthreads();
  }
#undef OSTAGE

#pragma unroll
  for (int fc = 0; fc < 4; fc++) {
    int n = n0 + fc * 16 + t;
    float bn = bo[n];
#pragma unroll
    for (int i = 0; i < 4; i++) {
      int m = m0 + w * 16 + qq * 4 + i;
      out[(size_t)m * NTOT + n] = acc[fc][i] + bn;
    }
  }
}

// ---------------------------------------------------------------------------
// Flash attention, swapped-QK^T 32x32x16, key-split wave pairs, fixed-max
// softmax (R15 verbatim).  Block = 8 waves (512 thr).
__global__ __launch_bounds__(512, 4) void flash_attn(const u16* __restrict__ Q,
                                                     const u16* __restrict__ Kg,
                                                     const u16* __restrict__ VT,
                                                     u16* __restrict__ O) {
  // XCD-chunked decode: each XCD owns 4 bh (2MB K/V -> L2-resident).
  const int e = blockIdx.x;            // 0..511
  const int xcd = e & 7, slot = e >> 3;
  const int bh = xcd * 4 + (slot & 3);
  const int qt = slot >> 2;            // 0..15

  const int tid = threadIdx.x, w = tid >> 6, ln = tid & 63;
  const int c = ln & 31, hi = ln >> 5;
  const int kb = w >> 2;               // key half of the pair
  const int q0 = qt * 128 + (w & 3) * 32;

  const u16* Qb = Q + (size_t)bh * SEQ * HD;
  const u16* Kb = Kg + (size_t)bh * SEQ * HD;
  const u16* Vb = VT + (size_t)bh * HD * SEQ;

  __shared__ __align__(16) u16 sK[3][64 * 64];   // 24 KB
  __shared__ __align__(16) u16 sV[3][64 * 64];   // 24 KB
  __shared__ float sml[8][64];                   // 2 KB

  // Q B-frags (hoisted): qf[ks] elem j = Q[q0+c][ks*16 + hi*8 + j]
  bf16x8 qf[4];
#pragma unroll
  for (int ks = 0; ks < 4; ks++)
    qf[ks] = ld_bf16x8(&Qb[(size_t)(q0 + c) * HD + ks * 16 + hi * 8]);

  f32x16 ot[2];
  ot[0] = 0.f; ot[1] = 0.f;
  float l = 0.f;

#define STAGE(pK, pV, kt)                                                      \
  {                                                                            \
    int ck = w * 64 + ln;                                                      \
    int r = ck >> 3, c2 = ck & 7, c2s = c2 ^ (r & 7);                          \
    stage16(&Kb[(size_t)((kt) + r) * HD + c2s * 8], (pK) + (size_t)(w * 64) * 8); \
    stage16(&Vb[(size_t)r * SEQ + (kt) + c2s * 8], (pV) + (size_t)(w * 64) * 8);  \
  }

#define QKT(stv, pK)                                                           \
  {                                                                            \
    stv = 0.f;                                                                 \
    __builtin_amdgcn_s_setprio(1);                                             \
    _Pragma("unroll") for (int ks = 0; ks < 4; ks++) {                         \
      int row = kb * 32 + c;                                                   \
      int boff = ((2 * ks + hi) ^ (row & 7)) << 4;                             \
      bf16x8 kf = ld_bf16x8((const u16*)((const char*)((pK) + row * 64) + boff)); \
      stv = __builtin_amdgcn_mfma_f32_32x32x16_bf16(kf, qf[ks], stv, 0, 0, 0); \
    }                                                                          \
    __builtin_amdgcn_s_setprio(0);                                             \
  }

// fixed-max softmax (base 2) + scalar-l sum tree + in-register repack + PV
#define SMAXPV(stv, pV)                                                        \
  {                                                                            \
    _Pragma("unroll") for (int i = 0; i < 16; i++)                             \
      stv[i] = fexp2(stv[i] - FMAX2);                                          \
    float u0 = (stv[0] + stv[1]) + (stv[2] + stv[3]);                          \
    float u1 = (stv[4] + stv[5]) + (stv[6] + stv[7]);                          \
    float u2 = (stv[8] + stv[9]) + (stv[10] + stv[11]);                        \
    float u3 = (stv[12] + stv[13]) + (stv[14] + stv[15]);                      \
    float rs = (u0 + u1) + (u2 + u3);                                          \
    l += rs + __shfl_xor(rs, 32);                                              \
    bf16x8 pb[2];                                                              \
    _Pragma("unroll") for (int ks2 = 0; ks2 < 2; ks2++) {                      \
      const int R0 = 8 * ks2;                                                  \
      const int R1 = 4 * ((2 * ks2 + 1) & 3);                                  \
      u32 X0 = cvtpk(stv[R0], stv[R0 + 1]);                                    \
      u32 X1 = cvtpk(stv[R0 + 2], stv[R0 + 3]);                                \
      u32 Y0 = cvtpk(stv[R1], stv[R1 + 1]);                                    \
      u32 Y1 = cvtpk(stv[R1 + 2], stv[R1 + 3]);                                \
      asm("v_permlane32_swap_b32 %0, %1" : "+v"(X0), "+v"(Y0));                \
      asm("v_permlane32_swap_b32 %0, %1" : "+v"(X1), "+v"(Y1));                \
      u32x4 wd; wd.x = X0; wd.y = X1; wd.z = Y0; wd.w = Y1;                    \
      pb[ks2] = __builtin_bit_cast(bf16x8, wd);                                \
    }                                                                          \
    __builtin_amdgcn_s_setprio(1);                                             \
    _Pragma("unroll") for (int ks2 = 0; ks2 < 2; ks2++) {                      \
      _Pragma("unroll") for (int db = 0; db < 2; db++) {                       \
        int row = db * 32 + c;                                                 \
        int boff = ((kb * 4 + ks2 * 2 + hi) ^ (row & 7)) << 4;                 \
        bf16x8 vf = ld_bf16x8((const u16*)((const char*)((pV) + row * 64) + boff)); \
        ot[db] = __builtin_amdgcn_mfma_f32_32x32x16_bf16(vf, pb[ks2], ot[db], 0, 0, 0); \
      }                                                                        \
    }                                                                          \
    __builtin_amdgcn_s_setprio(0);                                             \
  }

#define ROTATE()                                                               \
  { u16* x_ = kC; kC = kN; kN = kF; kF = x_;                                   \
    x_ = vC; vC = vN; vN = vF; vF = x_; }

  u16 *kC = sK[0], *kN = sK[1], *kF = sK[2];
  u16 *vC = sV[0], *vN = sV[1], *vF = sV[2];

  f32x16 stA, stB;

  // prologue: tile0 staged+visible; S(0) computed; tile1 staged+visible.
  STAGE(kC, vC, 0)
  __syncthreads();
  QKT(stA, kC)
  STAGE(kN, vN, 64)
  __syncthreads();

  for (int t = 0; t < 32; t += 2) {
    if (t + 2 < 32) STAGE(kF, vF, (t + 2) * 64)
    if (t + 1 < 32) QKT(stB, kN)
    SMAXPV(stA, vC)
    __syncthreads();
    ROTATE()
    if (t + 3 < 32) STAGE(kF, vF, (t + 3) * 64)
    if (t + 2 < 32) QKT(stA, kN)
    SMAXPV(stB, vC)
    __syncthreads();
    ROTATE()
  }
#undef STAGE
#undef QKT
#undef SMAXPV
#undef ROTATE

  // ---- pair merge (w <-> w^4) through LDS: plain adds, then store ----
  float myl = l;
  const int pair = w & 3;
  float* xA = (float*)sK;   // waves 0-3 deposit their ot[1] here (16 KB)
  float* xB = (float*)sV;   // waves 4-7 deposit their ot[0] here (16 KB)
  {
    f32x16 give = (w < 4) ? ot[1] : ot[0];
    *(f32x16*)((w < 4 ? xA : xB) + (size_t)(pair * 64 + ln) * 16) = give;
    sml[w][ln] = myl;
  }
  __syncthreads();

  float po = sml[w ^ 4][ln];
  float lf = myl + po;
  float inv = 1.0f / (lf * 32.0f);
  f32x16 oth = *(const f32x16*)((w < 4 ? xB : xA) + (size_t)(pair * 64 + ln) * 16);
  f32x16 own = (w < 4) ? ot[0] : ot[1];
  const int db = (w < 4) ? 0 : 1;

  const int b = bh >> 4, h = bh & 15;
  u16* obase = O + ((size_t)(b * SEQ + q0 + c)) * EMB + h * HD;
#pragma unroll
  for (int g = 0; g < 4; g++) {
    u16x4 pkt;
#pragma unroll
    for (int i = 0; i < 4; i++)
      pkt[i] = f2bf((own[g * 4 + i] + oth[g * 4 + i]) * inv);
    *(u16x4*)(obase + db * 32 + g * 8 + hi * 4) = pkt;
  }
}

// ---------------------------------------------------------------------------
extern "C" void kernel_launch(void* const* d_in, const int* in_sizes, int n_in,
                              void* d_out, int out_size, void* d_ws, size_t ws_size,
                              hipStream_t stream) {
  const float* x  = (const float*)d_in[0];
  const float* Wq = (const float*)d_in[1];
  const float* bq = (const float*)d_in[2];
  const float* Wk = (const float*)d_in[3];
  const float* bk = (const float*)d_in[4];
  const float* Wv = (const float*)d_in[5];
  const float* bv = (const float*)d_in[6];
  const float* Wo = (const float*)d_in[7];
  const float* bo = (const float*)d_in[8];

  char* ws = (char*)d_ws;
  u16* xbf = (u16*)(ws + OFF_XBF);   // x bf16; later reused as O
  u16* wqb = (u16*)(ws + OFF_WQ);
  u16* wkb = (u16*)(ws + OFF_WK);
  u16* wvb = (u16*)(ws + OFF_WV);
  u16* wob = (u16*)(ws + OFF_WO);
  u16* Qw  = (u16*)(ws + OFF_Q);
  u16* Kw  = (u16*)(ws + OFF_K);
  u16* Vw  = (u16*)(ws + OFF_VT);

  // 1) fp32 -> bf16 (x + 4 weights, one launch, exact grid)
  cvt_all<<<dim3(8192), 256, 0, stream>>>(x, Wq, Wk, Wv, Wo, xbf, wqb, wkb, wvb, wob);

  // 2) QKV projections, transposed grid (M-tiles fastest -> XCD = m%8)
  gemm_qkv<<<dim3(MTOT / 128, NTOT / 128, 3), 512, 0, stream>>>(
      xbf, wqb, wkb, wvb, bq, bk, bv, Qw, Kw, Vw);

  // 3) flash attention -> O (reuses xbf region)
  flash_attn<<<dim3(512), 512, 0, stream>>>(Qw, Kw, Vw, xbf);

  // 4) output projection -> d_out (fp32), 128x64 tiles = 512 blocks (2/CU)
  gemm_o<<<dim3(MTOT / 128, NTOT / 64), 512, 0, stream>>>(xbf, wob, bo, (float*)d_out);
}

// Round 18
// 110.616 us; speedup vs baseline: 1.0087x; 1.0087x over previous
//
#include <hip/hip_runtime.h>

// ---------------------------------------------------------------------------
// Attention_25254407701324: full MHA forward on MI355X (gfx950).
// B=2, N=2048, E=1024, H=16, D=64.  bf16 MFMA, fp32 accum.
// R18 = R16 verbatim (measured best, 110.3us):
//   cvt_all: exact-grid fused fp32->bf16 (HBM floor).
//   gemm_qkv / gemm_o: shared 128x128 8-wave dbuf core, transposed grid
//     (XCD = m-tile%8 -> panels L2-resident).  R10/R17 tile reshapes both
//     regressed; this core is the local optimum for these shapes.
//   flash: swapped-QK^T 32x32x16, key-split wave pairs, 3-buffer rotation,
//     fixed-max exp2(S-32) softmax (exact power-of-2 rescale), scalar-l.
// ---------------------------------------------------------------------------

typedef __bf16 bf16x8 __attribute__((ext_vector_type(8)));
typedef float  f32x4  __attribute__((ext_vector_type(4)));
typedef float  f32x16 __attribute__((ext_vector_type(16)));
using u16 = unsigned short;
using u32 = unsigned int;
typedef u16 u16x8 __attribute__((ext_vector_type(8)));
typedef u16 u16x4 __attribute__((ext_vector_type(4)));
typedef u32 u32x4 __attribute__((ext_vector_type(4)));

constexpr int BATCH = 2, SEQ = 2048, EMB = 1024, NH = 16, HD = 64;
constexpr int MTOT = BATCH * SEQ;      // 4096
constexpr int KTOT = EMB;              // 1024
constexpr int NTOT = EMB;              // 1024
constexpr float LOG2E = 1.44269504088896340736f;
constexpr float FMAX2 = 32.0f;         // fixed base-2 softmax shift

// ws layout (bytes)
constexpr size_t OFF_XBF = 0;                         // 8 MB (reused as O)
constexpr size_t OFF_WQ  = 8u * 1024 * 1024;
constexpr size_t OFF_WK  = OFF_WQ + 2u * 1024 * 1024;
constexpr size_t OFF_WV  = OFF_WK + 2u * 1024 * 1024;
constexpr size_t OFF_WO  = OFF_WV + 2u * 1024 * 1024;
constexpr size_t OFF_Q   = OFF_WO + 2u * 1024 * 1024; // 16 MB
constexpr size_t OFF_K   = OFF_Q  + 8u * 1024 * 1024;
constexpr size_t OFF_VT  = OFF_K  + 8u * 1024 * 1024; // ends at 40 MB

__device__ __forceinline__ u16 f2bf(float f) {
  u32 u = __builtin_bit_cast(u32, f);
  u = (u + 0x7fffu + ((u >> 16) & 1u)) >> 16;   // RNE
  return (u16)u;
}

__device__ __forceinline__ bf16x8 ld_bf16x8(const u16* p) {
  return __builtin_bit_cast(bf16x8, *(const u16x8*)p);
}

__device__ __forceinline__ float fexp2(float x) {
#if __has_builtin(__builtin_amdgcn_exp2f)
  return __builtin_amdgcn_exp2f(x);
#else
  return exp2f(x);
#endif
}

// packed f32x2 -> bf16x2 (RNE), low word = first arg
__device__ __forceinline__ u32 cvtpk(float lo, float hi_) {
  u32 r;
  asm("v_cvt_pk_bf16_f32 %0, %1, %2" : "=v"(r) : "v"(lo), "v"(hi_));
  return r;
}

// async global->LDS, 16B per lane. LDS dest = wave-uniform base + lane*16.
__device__ __forceinline__ void stage16(const void* g, void* l) {
#if __has_builtin(__builtin_amdgcn_global_load_lds)
  __builtin_amdgcn_global_load_lds(
      (__attribute__((address_space(1))) void*)const_cast<void*>(g),
      (__attribute__((address_space(3))) void*)l, 16, 0, 0);
#else
  int lane = threadIdx.x & 63;
  uint4 v = *(const uint4*)g;
  *(uint4*)((char*)l + lane * 16) = v;
#endif
}

// ---------------------------------------------------------------------------
// fp32 -> bf16 for x and the 4 weight matrices; exact flat grid (8192 blocks).
__global__ __launch_bounds__(256) void cvt_all(
    const float* __restrict__ x, const float* __restrict__ wq,
    const float* __restrict__ wk, const float* __restrict__ wv,
    const float* __restrict__ wo, u16* __restrict__ ox, u16* __restrict__ oq,
    u16* __restrict__ okk, u16* __restrict__ ov, u16* __restrict__ oo) {
  int id = blockIdx.x;
  const float* in;
  u16* out;
  int i;
  if (id < 4096) {                 // x: 4096 blocks
    in = x; out = ox; i = id * 256 + threadIdx.x;
  } else {                         // weights: 1024 blocks each
    int z = (id - 4096) >> 10, r = (id - 4096) & 1023;
    in = (z == 0) ? wq : (z == 1) ? wk : (z == 2) ? wv : wo;
    out = (z == 0) ? oq : (z == 1) ? okk : (z == 2) ? ov : oo;
    i = r * 256 + threadIdx.x;
  }
  float4 f = ((const float4*)in)[i];
  u32 lo = (u32)f2bf(f.x) | ((u32)f2bf(f.y) << 16);
  u32 hi = (u32)f2bf(f.z) | ((u32)f2bf(f.w) << 16);
  ((uint2*)out)[i] = make_uint2(lo, hi);
}

// ---------------------------------------------------------------------------
// C = A[M][K] * B^T + bias, Bm is [N][K].  128x128 tile, 8 waves (512 thr).
// Grid is (M/128, N/128): blockIdx.x = m-tile (XCD = m-tile % 8 -> panels
// L2-resident), blockIdx.y = n-tile.  Double-buffered LDS, 1 barrier/K-step.
// Runtime mode (branch ONLY in epilogue):
// 0: bf16 scatter -> [B][H][N][D] (Q,K; oscale applied before cvt)
// 1: bf16 -> [B][H][D][N] (V^T) via LDS-transpose epilogue, coalesced stores
// 2: fp32 row-major [M][N] -> out
__device__ __forceinline__ void gemm_bt_core(const u16* __restrict__ A,
                                             const u16* __restrict__ Bm,
                                             const float* __restrict__ bias,
                                             void* __restrict__ out, int mode,
                                             float oscale) {
  __shared__ __align__(16) u16 smem[2][2][128 * 32];   // [buf][A/B] 32 KB
  const int tid = threadIdx.x, w = tid >> 6, ln = tid & 63;
  const int wr = w >> 1, wc = w & 1, qq = ln >> 4, t = ln & 15;
  const int m0 = blockIdx.x * 128, n0 = blockIdx.y * 128;   // transposed grid

  f32x4 acc[2][4] = {};

#define GSTAGE(bi, kt)                                                         \
  {                                                                            \
    int ck = w * 64 + ln;                        /* 0..511 */                  \
    int r = ck >> 2, c2 = ck & 3;                                              \
    stage16(&A[(size_t)(m0 + r) * KTOT + (kt) + c2 * 8],                       \
            &smem[bi][0][(size_t)(w * 64) * 8]);                               \
    stage16(&Bm[(size_t)(n0 + r) * KTOT + (kt) + c2 * 8],                      \
            &smem[bi][1][(size_t)(w * 64) * 8]);                               \
  }

  GSTAGE(0, 0)
  __syncthreads();

  int bs = 0;
  for (int kt = 0; kt < KTOT; kt += 32, bs ^= 1) {
    if (kt + 32 < KTOT) GSTAGE(bs ^ 1, kt + 32)
    const u16* sA = smem[bs][0];
    const u16* sB = smem[bs][1];

    bf16x8 av[2], bv[4];
#pragma unroll
    for (int f = 0; f < 2; f++)
      av[f] = ld_bf16x8(&sA[(wr * 32 + f * 16 + t) * 32 + qq * 8]);
#pragma unroll
    for (int f = 0; f < 4; f++)
      bv[f] = ld_bf16x8(&sB[(wc * 64 + f * 16 + t) * 32 + qq * 8]);
#pragma unroll
    for (int i = 0; i < 2; i++)
#pragma unroll
      for (int j = 0; j < 4; j++)
        acc[i][j] = __builtin_amdgcn_mfma_f32_16x16x32_bf16(av[i], bv[j], acc[i][j], 0, 0, 0);
    __syncthreads();   // stage(bs^1) landed; all reads of smem[bs] done
  }
#undef GSTAGE

  if (mode == 1) {
    // V^T: transpose the 128x128 tile through LDS (two 64-n-row phases),
    // then store tok-contiguous 16B/lane (256B segments).
    u16* tb = (u16*)smem;                       // 16 KB: [64 n][128 m] bf16
    const int b = m0 >> 11;
    const int t16 = tid & 15;
    const int tokb = (m0 & 2047) + t16 * 8;
#pragma unroll
    for (int ph = 0; ph < 2; ph++) {
      if (ph == 1) __syncthreads();             // protect ph0 reads
      if (wc == ph) {
#pragma unroll
        for (int fc = 0; fc < 4; fc++) {
          int nl = fc * 16 + t;
          float bn = bias[n0 + ph * 64 + nl];
#pragma unroll
          for (int fr = 0; fr < 2; fr++)
#pragma unroll
            for (int i = 0; i < 4; i++) {
              int ml = wr * 32 + fr * 16 + qq * 4 + i;
              tb[nl * 128 + (ml ^ ((nl & 7) << 4))] = f2bf(acc[fr][fc][i] + bn);
            }
        }
      }
      __syncthreads();
      // 512 threads: 32 rows/pass x 16 lanes, 2 passes -> 64 rows
#pragma unroll
      for (int p = 0; p < 2; p++) {
        int row = p * 32 + (tid >> 4);          // 0..63
        int n = n0 + ph * 64 + row;
        int hh = n >> 6, d = n & 63;
        u16x8 vd = *(const u16x8*)&tb[row * 128 + ((t16 * 8) ^ ((row & 7) << 4))];
        *(u16x8*)&((u16*)out)[(((size_t)(b * NH + hh)) * HD + d) * SEQ + tokb] = vd;
      }
    }
    return;
  }

#pragma unroll
  for (int fc = 0; fc < 4; fc++) {
    int n = n0 + wc * 64 + fc * 16 + t;
    float bn = bias[n];
#pragma unroll
    for (int fr = 0; fr < 2; fr++) {
#pragma unroll
      for (int i = 0; i < 4; i++) {
        int m = m0 + wr * 32 + fr * 16 + qq * 4 + i;
        float v = (acc[fr][fc][i] + bn) * oscale;
        if (mode == 2) {
          ((float*)out)[(size_t)m * NTOT + n] = v;
        } else {
          int b = m >> 11, tok = m & 2047, h = n >> 6, d = n & 63;
          ((u16*)out)[(((size_t)(b * NH + h)) * SEQ + tok) * HD + d] = f2bf(v);
        }
      }
    }
  }
}

// One launch, 3 z-slices, ONE call site -> one shared body.
__global__ __launch_bounds__(512) void gemm_qkv(
    const u16* __restrict__ A, const u16* __restrict__ WQ, const u16* __restrict__ WK,
    const u16* __restrict__ WV, const float* __restrict__ bq, const float* __restrict__ bk,
    const float* __restrict__ bv, u16* Qo, u16* Ko, u16* Vo) {
  int z = blockIdx.z;
  const u16* Bm = (z == 0) ? WQ : ((z == 1) ? WK : WV);
  const float* bias = (z == 0) ? bq : ((z == 1) ? bk : bv);
  u16* out = (z == 0) ? Qo : ((z == 1) ? Ko : Vo);
  // Q pre-scaled by log2(e) so flash softmax runs in base-2.
  gemm_bt_core(A, Bm, bias, out, (z == 2) ? 1 : 0, (z == 0) ? LOG2E : 1.0f);
}

__global__ __launch_bounds__(512) void gemm_o(const u16* __restrict__ A,
                                              const u16* __restrict__ WO,
                                              const float* __restrict__ bo,
                                              float* __restrict__ out) {
  gemm_bt_core(A, WO, bo, out, 2, 1.0f);
}

// ---------------------------------------------------------------------------
// Flash attention, swapped-QK^T 32x32x16, key-split wave pairs, fixed-max
// softmax (R15 structure).  Block = 8 waves (512 thr).
__global__ __launch_bounds__(512, 4) void flash_attn(const u16* __restrict__ Q,
                                                     const u16* __restrict__ Kg,
                                                     const u16* __restrict__ VT,
                                                     u16* __restrict__ O) {
  // XCD-chunked decode: each XCD owns 4 bh (2MB K/V -> L2-resident).
  const int e = blockIdx.x;            // 0..511
  const int xcd = e & 7, slot = e >> 3;
  const int bh = xcd * 4 + (slot & 3);
  const int qt = slot >> 2;            // 0..15

  const int tid = threadIdx.x, w = tid >> 6, ln = tid & 63;
  const int c = ln & 31, hi = ln >> 5;
  const int kb = w >> 2;               // key half of the pair
  const int q0 = qt * 128 + (w & 3) * 32;

  const u16* Qb = Q + (size_t)bh * SEQ * HD;
  const u16* Kb = Kg + (size_t)bh * SEQ * HD;
  const u16* Vb = VT + (size_t)bh * HD * SEQ;

  __shared__ __align__(16) u16 sK[3][64 * 64];   // 24 KB
  __shared__ __align__(16) u16 sV[3][64 * 64];   // 24 KB
  __shared__ float sml[8][64];                   // 2 KB

  // Q B-frags (hoisted): qf[ks] elem j = Q[q0+c][ks*16 + hi*8 + j]
  bf16x8 qf[4];
#pragma unroll
  for (int ks = 0; ks < 4; ks++)
    qf[ks] = ld_bf16x8(&Qb[(size_t)(q0 + c) * HD + ks * 16 + hi * 8]);

  f32x16 ot[2];
  ot[0] = 0.f; ot[1] = 0.f;
  float l = 0.f;

#define STAGE(pK, pV, kt)                                                      \
  {                                                                            \
    int ck = w * 64 + ln;                                                      \
    int r = ck >> 3, c2 = ck & 7, c2s = c2 ^ (r & 7);                          \
    stage16(&Kb[(size_t)((kt) + r) * HD + c2s * 8], (pK) + (size_t)(w * 64) * 8); \
    stage16(&Vb[(size_t)r * SEQ + (kt) + c2s * 8], (pV) + (size_t)(w * 64) * 8);  \
  }

#define QKT(stv, pK)                                                           \
  {                                                                            \
    stv = 0.f;                                                                 \
    __builtin_amdgcn_s_setprio(1);                                             \
    _Pragma("unroll") for (int ks = 0; ks < 4; ks++) {                         \
      int row = kb * 32 + c;                                                   \
      int boff = ((2 * ks + hi) ^ (row & 7)) << 4;                             \
      bf16x8 kf = ld_bf16x8((const u16*)((const char*)((pK) + row * 64) + boff)); \
      stv = __builtin_amdgcn_mfma_f32_32x32x16_bf16(kf, qf[ks], stv, 0, 0, 0); \
    }                                                                          \
    __builtin_amdgcn_s_setprio(0);                                             \
  }

// fixed-max softmax (base 2) + scalar-l sum tree + in-register repack + PV
#define SMAXPV(stv, pV)                                                        \
  {                                                                            \
    _Pragma("unroll") for (int i = 0; i < 16; i++)                             \
      stv[i] = fexp2(stv[i] - FMAX2);                                          \
    float u0 = (stv[0] + stv[1]) + (stv[2] + stv[3]);                          \
    float u1 = (stv[4] + stv[5]) + (stv[6] + stv[7]);                          \
    float u2 = (stv[8] + stv[9]) + (stv[10] + stv[11]);                        \
    float u3 = (stv[12] + stv[13]) + (stv[14] + stv[15]);                      \
    float rs = (u0 + u1) + (u2 + u3);                                          \
    l += rs + __shfl_xor(rs, 32);                                              \
    bf16x8 pb[2];                                                              \
    _Pragma("unroll") for (int ks2 = 0; ks2 < 2; ks2++) {                      \
      const int R0 = 8 * ks2;                                                  \
      const int R1 = 4 * ((2 * ks2 + 1) & 3);                                  \
      u32 X0 = cvtpk(stv[R0], stv[R0 + 1]);                                    \
      u32 X1 = cvtpk(stv[R0 + 2], stv[R0 + 3]);                                \
      u32 Y0 = cvtpk(stv[R1], stv[R1 + 1]);                                    \
      u32 Y1 = cvtpk(stv[R1 + 2], stv[R1 + 3]);                                \
      asm("v_permlane32_swap_b32 %0, %1" : "+v"(X0), "+v"(Y0));                \
      asm("v_permlane32_swap_b32 %0, %1" : "+v"(X1), "+v"(Y1));                \
      u32x4 wd; wd.x = X0; wd.y = X1; wd.z = Y0; wd.w = Y1;                    \
      pb[ks2] = __builtin_bit_cast(bf16x8, wd);                                \
    }                                                                          \
    __builtin_amdgcn_s_setprio(1);                                             \
    _Pragma("unroll") for (int ks2 = 0; ks2 < 2; ks2++) {                      \
      _Pragma("unroll") for (int db = 0; db < 2; db++) {                       \
        int row = db * 32 + c;                                                 \
        int boff = ((kb * 4 + ks2 * 2 + hi) ^ (row & 7)) << 4;                 \
        bf16x8 vf = ld_bf16x8((const u16*)((const char*)((pV) + row * 64) + boff)); \
        ot[db] = __builtin_amdgcn_mfma_f32_32x32x16_bf16(vf, pb[ks2], ot[db], 0, 0, 0); \
      }                                                                        \
    }                                                                          \
    __builtin_amdgcn_s_setprio(0);                                             \
  }

#define ROTATE()                                                               \
  { u16* x_ = kC; kC = kN; kN = kF; kF = x_;                                   \
    x_ = vC; vC = vN; vN = vF; vF = x_; }

  u16 *kC = sK[0], *kN = sK[1], *kF = sK[2];
  u16 *vC = sV[0], *vN = sV[1], *vF = sV[2];

  f32x16 stA, stB;

  // prologue: tile0 staged+visible; S(0) computed; tile1 staged+visible.
  STAGE(kC, vC, 0)
  __syncthreads();
  QKT(stA, kC)
  STAGE(kN, vN, 64)
  __syncthreads();

  for (int t = 0; t < 32; t += 2) {
    if (t + 2 < 32) STAGE(kF, vF, (t + 2) * 64)
    if (t + 1 < 32) QKT(stB, kN)
    SMAXPV(stA, vC)
    __syncthreads();
    ROTATE()
    if (t + 3 < 32) STAGE(kF, vF, (t + 3) * 64)
    if (t + 2 < 32) QKT(stA, kN)
    SMAXPV(stB, vC)
    __syncthreads();
    ROTATE()
  }
#undef STAGE
#undef QKT
#undef SMAXPV
#undef ROTATE

  // ---- pair merge (w <-> w^4) through LDS: plain adds, then store ----
  float myl = l;
  const int pair = w & 3;
  float* xA = (float*)sK;   // waves 0-3 deposit their ot[1] here (16 KB)
  float* xB = (float*)sV;   // waves 4-7 deposit their ot[0] here (16 KB)
  {
    f32x16 give = (w < 4) ? ot[1] : ot[0];
    *(f32x16*)((w < 4 ? xA : xB) + (size_t)(pair * 64 + ln) * 16) = give;
    sml[w][ln] = myl;
  }
  __syncthreads();

  float po = sml[w ^ 4][ln];
  float lf = myl + po;
  float inv = 1.0f / (lf * 32.0f);
  f32x16 oth = *(const f32x16*)((w < 4 ? xB : xA) + (size_t)(pair * 64 + ln) * 16);
  f32x16 own = (w < 4) ? ot[0] : ot[1];
  const int db = (w < 4) ? 0 : 1;

  const int b = bh >> 4, h = bh & 15;
  u16* obase = O + ((size_t)(b * SEQ + q0 + c)) * EMB + h * HD;
#pragma unroll
  for (int g = 0; g < 4; g++) {
    u16x4 pkt;
#pragma unroll
    for (int i = 0; i < 4; i++)
      pkt[i] = f2bf((own[g * 4 + i] + oth[g * 4 + i]) * inv);
    *(u16x4*)(obase + db * 32 + g * 8 + hi * 4) = pkt;
  }
}

// ---------------------------------------------------------------------------
extern "C" void kernel_launch(void* const* d_in, const int* in_sizes, int n_in,
                              void* d_out, int out_size, void* d_ws, size_t ws_size,
                              hipStream_t stream) {
  const float* x  = (const float*)d_in[0];
  const float* Wq = (const float*)d_in[1];
  const float* bq = (const float*)d_in[2];
  const float* Wk = (const float*)d_in[3];
  const float* bk = (const float*)d_in[4];
  const float* Wv = (const float*)d_in[5];
  const float* bv = (const float*)d_in[6];
  const float* Wo = (const float*)d_in[7];
  const float* bo = (const float*)d_in[8];

  char* ws = (char*)d_ws;
  u16* xbf = (u16*)(ws + OFF_XBF);   // x bf16; later reused as O
  u16* wqb = (u16*)(ws + OFF_WQ);
  u16* wkb = (u16*)(ws + OFF_WK);
  u16* wvb = (u16*)(ws + OFF_WV);
  u16* wob = (u16*)(ws + OFF_WO);
  u16* Qw  = (u16*)(ws + OFF_Q);
  u16* Kw  = (u16*)(ws + OFF_K);
  u16* Vw  = (u16*)(ws + OFF_VT);

  // 1) fp32 -> bf16 (x + 4 weights, one launch, exact grid)
  cvt_all<<<dim3(8192), 256, 0, stream>>>(x, Wq, Wk, Wv, Wo, xbf, wqb, wkb, wvb, wob);

  // 2) QKV projections, transposed grid (M-tiles fastest -> XCD = m%8)
  gemm_qkv<<<dim3(MTOT / 128, NTOT / 128, 3), 512, 0, stream>>>(
      xbf, wqb, wkb, wvb, bq, bk, bv, Qw, Kw, Vw);

  // 3) flash attention -> O (reuses xbf region)
  flash_attn<<<dim3(512), 512, 0, stream>>>(Qw, Kw, Vw, xbf);

  // 4) output projection -> d_out (fp32), transposed grid, 128x128 tiles
  gemm_o<<<dim3(MTOT / 128, NTOT / 128), 512, 0, stream>>>(xbf, wob, bo, (float*)d_out);
}